// Round 2
// baseline (938.210 us; speedup 1.0000x reference)
//
#include <hip/hip_runtime.h>
#include <cmath>

#define DF 128           // feature dim
#define TR 128           // gemm rows per block tile
#define KC 32            // gemm K chunk staged in LDS
#define PITCH 36         // LDS row pitch in floats (32 data + 4 pad, 144 B = 16B-aligned)

// ---------------------------------------------------------------------------
// Kernel 1: support[n][o] = sum_d X[n][d] * W[o][d] + b[o]
// 256 threads, 128x128 tile, 8x8 register tile per thread with STRIDED
// ownership: rows r = ty+16i, cols c = tx+16j. Within a wave (ty spans 4
// consecutive values, tx 16), X-fragment reads hit 4 consecutive LDS rows
// (bank quads 0/4/8/12 -> conflict-free) and W-fragment reads stride one
// pitch (2-way alias -> free). All LDS offsets are compile-time affine ->
// no spill pressure.
// ---------------------------------------------------------------------------
__global__ __launch_bounds__(256, 4)
void gemm_bias_kernel(const float* __restrict__ X, const float* __restrict__ W,
                      const float* __restrict__ bias, float* __restrict__ S,
                      int N)
{
    __shared__ float Xs[TR * PITCH];   // 18.0 KB
    __shared__ float Ws[DF * PITCH];   // 18.0 KB

    const int t  = threadIdx.x;
    const int tx = t & 15;             // cols: tx + 16*j
    const int ty = t >> 4;             // rows: ty + 16*i   (4 consecutive per wave)
    const int r0 = blockIdx.x * TR;

    float acc[8][8];
    #pragma unroll
    for (int i = 0; i < 8; ++i)
        #pragma unroll
        for (int j = 0; j < 8; ++j) acc[i][j] = 0.f;

    for (int kc = 0; kc < DF; kc += KC) {
        // ---- stage X chunk: rows r0..r0+127, d in [kc, kc+32) ----
        #pragma unroll
        for (int l = 0; l < 4; ++l) {
            int idx = (l * 256 + t) * 4;          // [0, 128*32)
            int r   = idx >> 5;
            int dl  = idx & 31;
            float4 v = make_float4(0.f, 0.f, 0.f, 0.f);
            int gr = r0 + r;
            if (gr < N) v = *(const float4*)(X + (size_t)gr * DF + kc + dl);
            *(float4*)(Xs + r * PITCH + dl) = v;
        }
        // ---- stage W chunk: rows (=out cols) 0..127, d in [kc, kc+32) ----
        #pragma unroll
        for (int l = 0; l < 4; ++l) {
            int idx = (l * 256 + t) * 4;
            int c   = idx >> 5;
            int dl  = idx & 31;
            float4 v = *(const float4*)(W + (size_t)c * DF + kc + dl);
            *(float4*)(Ws + c * PITCH + dl) = v;
        }
        __syncthreads();

        // ---- accumulate over the 32-wide chunk, 4 floats at a time ----
        #pragma unroll
        for (int dt = 0; dt < KC; dt += 4) {
            float4 xv[8];
            #pragma unroll
            for (int i = 0; i < 8; ++i)
                xv[i] = *(const float4*)(Xs + (ty + 16 * i) * PITCH + dt);
            #pragma unroll
            for (int j = 0; j < 8; ++j) {
                float4 wv = *(const float4*)(Ws + (tx + 16 * j) * PITCH + dt);
                #pragma unroll
                for (int i = 0; i < 8; ++i) {
                    acc[i][j] += xv[i].x * wv.x + xv[i].y * wv.y
                               + xv[i].z * wv.z + xv[i].w * wv.w;
                }
            }
        }
        __syncthreads();
    }

    // ---- epilogue: add bias, scalar stores (strided cols) ----
    float bj[8];
    #pragma unroll
    for (int j = 0; j < 8; ++j) bj[j] = bias[tx + 16 * j];
    #pragma unroll
    for (int i = 0; i < 8; ++i) {
        int gr = r0 + ty + 16 * i;
        if (gr < N) {
            float* row = S + (size_t)gr * DF;
            #pragma unroll
            for (int j = 0; j < 8; ++j)
                row[tx + 16 * j] = acc[i][j] + bj[j];
        }
    }
}

// ---------------------------------------------------------------------------
// Kernel 2: CSR row-pointer build from sorted adj_row.
// rowptr[n] = first edge index e with adj_row[e] >= n;  rowptr[N] = E.
// ---------------------------------------------------------------------------
__global__ __launch_bounds__(256)
void build_rowptr_kernel(const int* __restrict__ arow, int* __restrict__ rowptr,
                         int N, int E)
{
    int e = blockIdx.x * 256 + threadIdx.x;
    if (e >= E) return;
    int r = arow[e];
    int rprev = (e == 0) ? -1 : arow[e - 1];
    for (int n = rprev + 1; n <= r; ++n) rowptr[n] = e;
    if (e == E - 1) {
        for (int n = r + 1; n <= N; ++n) rowptr[n] = E;
    }
}

// ---------------------------------------------------------------------------
// Kernel 3: out[n][:] = tanh( sum_{e in [rowptr[n],rowptr[n+1])} aval[e]*S[acol[e]][:] )
// One 64-lane wave per node; lane L holds features 2L,2L+1 (float2) so each
// edge gather is one fully-coalesced 512 B row read. Inner loop unrolled 4x
// (zero-padded lanes) for memory-level parallelism.
// ---------------------------------------------------------------------------
__global__ __launch_bounds__(256)
void agg_tanh_kernel(const float* __restrict__ S, const int* __restrict__ rowptr,
                     const int* __restrict__ acol, const float* __restrict__ aval,
                     float* __restrict__ out, int Nn)
{
    const int n    = (int)((blockIdx.x * 256u + threadIdx.x) >> 6);
    const int lane = threadIdx.x & 63;
    if (n >= Nn) return;

    const int start = rowptr[n];
    const int end   = rowptr[n + 1];

    float2 acc; acc.x = 0.f; acc.y = 0.f;
    for (int base = start; base < end; base += 64) {
        int   col = 0;
        float val = 0.f;
        if (base + lane < end) {
            col = acol[base + lane];
            val = aval[base + lane];
        }
        int cntp = min(64, end - base);
        cntp = (cntp + 3) & ~3;                    // pad to 4 (padded lanes: val=0)
        for (int i = 0; i < cntp; i += 4) {
            const int   c0 = __shfl(col, i);
            const int   c1 = __shfl(col, i + 1);
            const int   c2 = __shfl(col, i + 2);
            const int   c3 = __shfl(col, i + 3);
            const float v0 = __shfl(val, i);
            const float v1 = __shfl(val, i + 1);
            const float v2 = __shfl(val, i + 2);
            const float v3 = __shfl(val, i + 3);
            const float2 s0 = *(const float2*)(S + (size_t)c0 * DF + lane * 2);
            const float2 s1 = *(const float2*)(S + (size_t)c1 * DF + lane * 2);
            const float2 s2 = *(const float2*)(S + (size_t)c2 * DF + lane * 2);
            const float2 s3 = *(const float2*)(S + (size_t)c3 * DF + lane * 2);
            acc.x += v0 * s0.x; acc.y += v0 * s0.y;
            acc.x += v1 * s1.x; acc.y += v1 * s1.y;
            acc.x += v2 * s2.x; acc.y += v2 * s2.y;
            acc.x += v3 * s3.x; acc.y += v3 * s3.y;
        }
    }

    float2 o;
    o.x = tanhf(acc.x);
    o.y = tanhf(acc.y);
    *(float2*)(out + (size_t)n * DF + lane * 2) = o;
}

// ---------------------------------------------------------------------------
extern "C" void kernel_launch(void* const* d_in, const int* in_sizes, int n_in,
                              void* d_out, int out_size, void* d_ws, size_t ws_size,
                              hipStream_t stream)
{
    const float* X    = (const float*)d_in[0];   // [N, 128]
    const float* W    = (const float*)d_in[1];   // [128, 128]
    const float* bias = (const float*)d_in[2];   // [128]
    const int*   arow = (const int*)  d_in[3];   // [E] sorted
    const int*   acol = (const int*)  d_in[4];   // [E]
    const float* aval = (const float*)d_in[5];   // [E]
    float* out = (float*)d_out;

    const int N = in_sizes[0] / DF;
    const int E = in_sizes[3];

    float* S      = (float*)d_ws;                        // N*128 fp32 = 25.6 MB
    int*   rowptr = (int*)d_ws + (size_t)N * DF;         // N+1 ints

    build_rowptr_kernel<<<(E + 255) / 256, 256, 0, stream>>>(arow, rowptr, N, E);

    gemm_bias_kernel<<<(N + TR - 1) / TR, 256, 0, stream>>>(X, W, bias, S, N);

    agg_tanh_kernel<<<(N * 64 + 255) / 256, 256, 0, stream>>>(S, rowptr, acol, aval, out, N);
}

// Round 3
// 200.820 us; speedup vs baseline: 4.6719x; 4.6719x over previous
//
#include <hip/hip_runtime.h>
#include <cmath>

#define DF 128           // feature dim
#define TR 64            // gemm rows per block tile
#define KC 32            // gemm K chunk staged in LDS
#define PITCH 36         // LDS row pitch in floats (32 data + 4 pad, 144 B, 16B-aligned)

// ---------------------------------------------------------------------------
// Kernel 1: support[n][o] = sum_d X[n][d] * W[o][d] + b[o]
// 256 threads, 64x128 tile, 4x8 register tile per thread (32-float acc, no
// spill). Rows: r = ty + 16*i (ty=t>>4). Cols: c = 4*tx + u + 64*h
// (tx=t&15, u=0..3, h=0..1) -> consecutive float4 col chunks => float4
// epilogue stores. LDS reads: X-frag rows ty+16i: bank quad (4*ty+...)
// distinct per ty -> conflict-free; W-frag rows 4tx+u+64h: quad 16*tx mod 32
// = {0,16} -> 2-way alias (free per m136).
// ---------------------------------------------------------------------------
__global__ __launch_bounds__(256)
void gemm_bias_kernel(const float* __restrict__ X, const float* __restrict__ W,
                      const float* __restrict__ bias, float* __restrict__ S,
                      int N)
{
    __shared__ float Xs[TR * PITCH];   //  9.0 KB
    __shared__ float Ws[DF * PITCH];   // 18.0 KB

    const int t  = threadIdx.x;
    const int tx = t & 15;
    const int ty = t >> 4;
    const int r0 = blockIdx.x * TR;

    float acc[4][8];
    #pragma unroll
    for (int i = 0; i < 4; ++i)
        #pragma unroll
        for (int j = 0; j < 8; ++j) acc[i][j] = 0.f;

    for (int kc = 0; kc < DF; kc += KC) {
        // ---- stage X chunk: rows r0..r0+63, d in [kc, kc+32) ----
        #pragma unroll
        for (int l = 0; l < 2; ++l) {
            int idx = (l * 256 + t) * 4;          // [0, 64*32)
            int r   = idx >> 5;
            int dl  = idx & 31;
            float4 v = make_float4(0.f, 0.f, 0.f, 0.f);
            int gr = r0 + r;
            if (gr < N) v = *(const float4*)(X + (size_t)gr * DF + kc + dl);
            *(float4*)(Xs + r * PITCH + dl) = v;
        }
        // ---- stage W chunk: out-cols 0..127, d in [kc, kc+32) ----
        #pragma unroll
        for (int l = 0; l < 4; ++l) {
            int idx = (l * 256 + t) * 4;
            int c   = idx >> 5;
            int dl  = idx & 31;
            float4 v = *(const float4*)(W + (size_t)c * DF + kc + dl);
            *(float4*)(Ws + c * PITCH + dl) = v;
        }
        __syncthreads();

        // ---- accumulate over the 32-wide chunk, 4 k at a time ----
        #pragma unroll
        for (int dt = 0; dt < KC; dt += 4) {
            float4 xv[4];
            #pragma unroll
            for (int i = 0; i < 4; ++i)
                xv[i] = *(const float4*)(Xs + (ty + 16 * i) * PITCH + dt);
            #pragma unroll
            for (int h = 0; h < 2; ++h) {
                float4 wv[4];
                #pragma unroll
                for (int u = 0; u < 4; ++u)
                    wv[u] = *(const float4*)(Ws + (4 * tx + u + 64 * h) * PITCH + dt);
                #pragma unroll
                for (int i = 0; i < 4; ++i)
                    #pragma unroll
                    for (int u = 0; u < 4; ++u) {
                        acc[i][h * 4 + u] += xv[i].x * wv[u].x + xv[i].y * wv[u].y
                                           + xv[i].z * wv[u].z + xv[i].w * wv[u].w;
                    }
            }
        }
        __syncthreads();
    }

    // ---- epilogue: add bias, two coalesced float4 stores per row ----
    float4 b0 = *(const float4*)(bias + 4 * tx);
    float4 b1 = *(const float4*)(bias + 4 * tx + 64);
    #pragma unroll
    for (int i = 0; i < 4; ++i) {
        int gr = r0 + ty + 16 * i;
        if (gr < N) {
            float4 o0, o1;
            o0.x = acc[i][0] + b0.x; o0.y = acc[i][1] + b0.y;
            o0.z = acc[i][2] + b0.z; o0.w = acc[i][3] + b0.w;
            o1.x = acc[i][4] + b1.x; o1.y = acc[i][5] + b1.y;
            o1.z = acc[i][6] + b1.z; o1.w = acc[i][7] + b1.w;
            *(float4*)(S + (size_t)gr * DF + 4 * tx)      = o0;
            *(float4*)(S + (size_t)gr * DF + 4 * tx + 64) = o1;
        }
    }
}

// ---------------------------------------------------------------------------
// Kernel 2: CSR row-pointer build from sorted adj_row.
// ---------------------------------------------------------------------------
__global__ __launch_bounds__(256)
void build_rowptr_kernel(const int* __restrict__ arow, int* __restrict__ rowptr,
                         int N, int E)
{
    int e = blockIdx.x * 256 + threadIdx.x;
    if (e >= E) return;
    int r = arow[e];
    int rprev = (e == 0) ? -1 : arow[e - 1];
    for (int n = rprev + 1; n <= r; ++n) rowptr[n] = e;
    if (e == E - 1) {
        for (int n = r + 1; n <= N; ++n) rowptr[n] = E;
    }
}

// ---------------------------------------------------------------------------
// Kernel 3: out[n][:] = tanh( sum_e aval[e]*S[acol[e]][:] )  per CSR segment.
// 32 lanes per node, float4 per lane (512 B per edge-row, fully coalesced).
// 2 nodes per wave -> 2 independent gather chains; 4x edge unroll -> up to 8
// loads in flight per wave.
// ---------------------------------------------------------------------------
__global__ __launch_bounds__(256)
void agg_tanh_kernel(const float* __restrict__ S, const int* __restrict__ rowptr,
                     const int* __restrict__ acol, const float* __restrict__ aval,
                     float* __restrict__ out, int Nn)
{
    const int sub = threadIdx.x >> 5;          // 0..7 half-wave in block
    const int l32 = threadIdx.x & 31;
    const int n   = blockIdx.x * 8 + sub;
    if (n >= Nn) return;

    const int start = rowptr[n];
    const int end   = rowptr[n + 1];

    float4 acc = make_float4(0.f, 0.f, 0.f, 0.f);
    for (int base = start; base < end; base += 32) {
        int   col = 0;
        float val = 0.f;
        if (base + l32 < end) {
            col = acol[base + l32];
            val = aval[base + l32];
        }
        int cntp = min(32, end - base);
        cntp = (cntp + 3) & ~3;                // pad to 4 (padded lanes val=0)
        for (int i = 0; i < cntp; i += 4) {
            const int   c0 = __shfl(col, i,     32);
            const int   c1 = __shfl(col, i + 1, 32);
            const int   c2 = __shfl(col, i + 2, 32);
            const int   c3 = __shfl(col, i + 3, 32);
            const float v0 = __shfl(val, i,     32);
            const float v1 = __shfl(val, i + 1, 32);
            const float v2 = __shfl(val, i + 2, 32);
            const float v3 = __shfl(val, i + 3, 32);
            const float4 s0 = *(const float4*)(S + (size_t)c0 * DF + l32 * 4);
            const float4 s1 = *(const float4*)(S + (size_t)c1 * DF + l32 * 4);
            const float4 s2 = *(const float4*)(S + (size_t)c2 * DF + l32 * 4);
            const float4 s3 = *(const float4*)(S + (size_t)c3 * DF + l32 * 4);
            acc.x += v0 * s0.x; acc.y += v0 * s0.y; acc.z += v0 * s0.z; acc.w += v0 * s0.w;
            acc.x += v1 * s1.x; acc.y += v1 * s1.y; acc.z += v1 * s1.z; acc.w += v1 * s1.w;
            acc.x += v2 * s2.x; acc.y += v2 * s2.y; acc.z += v2 * s2.z; acc.w += v2 * s2.w;
            acc.x += v3 * s3.x; acc.y += v3 * s3.y; acc.z += v3 * s3.z; acc.w += v3 * s3.w;
        }
    }

    float4 o;
    o.x = tanhf(acc.x); o.y = tanhf(acc.y);
    o.z = tanhf(acc.z); o.w = tanhf(acc.w);
    *(float4*)(out + (size_t)n * DF + l32 * 4) = o;
}

// ---------------------------------------------------------------------------
extern "C" void kernel_launch(void* const* d_in, const int* in_sizes, int n_in,
                              void* d_out, int out_size, void* d_ws, size_t ws_size,
                              hipStream_t stream)
{
    const float* X    = (const float*)d_in[0];   // [N, 128]
    const float* W    = (const float*)d_in[1];   // [128, 128]
    const float* bias = (const float*)d_in[2];   // [128]
    const int*   arow = (const int*)  d_in[3];   // [E] sorted
    const int*   acol = (const int*)  d_in[4];   // [E]
    const float* aval = (const float*)d_in[5];   // [E]
    float* out = (float*)d_out;

    const int N = in_sizes[0] / DF;
    const int E = in_sizes[3];

    float* S      = (float*)d_ws;                        // N*128 fp32 = 25.6 MB
    int*   rowptr = (int*)d_ws + (size_t)N * DF;         // N+1 ints

    build_rowptr_kernel<<<(E + 255) / 256, 256, 0, stream>>>(arow, rowptr, N, E);

    gemm_bias_kernel<<<(N + TR - 1) / TR, 256, 0, stream>>>(X, W, bias, S, N);

    agg_tanh_kernel<<<(N + 7) / 8, 256, 0, stream>>>(S, rowptr, acol, aval, out, N);
}

// Round 4
// 154.722 us; speedup vs baseline: 6.0638x; 1.2979x over previous
//
#include <hip/hip_runtime.h>
#include <cmath>

#define DF 128           // feature dim
#define TR 128           // gemm rows per block tile
#define KC 32            // gemm K chunk staged in LDS

// ---------------------------------------------------------------------------
// Kernel 1: support[n][o] = sum_d X[n][d] * W[o][d] + b[o]
// 256 threads, 128x128 tile, 8x8 register tile per thread.
// LDS holds TRANSPOSED chunks: Xs[k][m] and Ws[k][n], pitch 128 (16 KB each).
// Fragment reads at fixed k:
//   X: addr = k*128 + 8*ty  -> wave's 4 ty values hit quads {0,2,4,6}(+1 for
//      the second b128) with 16-lane broadcast -> conflict-free.
//   W: addr = k*128 + 4*tx (+64) -> 4*tx spreads all 32 banks, tx and tx+8
//      differ by 32 dwords -> 2-way alias (free, m136).
// Staging transposes with 4 scalar writes; write bank = r mod 32 with r
// lane-consecutive -> 2-way alias (free). No runtime-variable swizzle ->
// no spill pressure.
// ---------------------------------------------------------------------------
__global__ __launch_bounds__(256)
void gemm_bias_kernel(const float* __restrict__ X, const float* __restrict__ W,
                      const float* __restrict__ bias, float* __restrict__ S,
                      int N)
{
    __shared__ float Xs[KC * 128];   // 16 KB  [k][m]
    __shared__ float Ws[KC * 128];   // 16 KB  [k][n]

    const int t  = threadIdx.x;
    const int tx = t & 15;           // cols 4*tx..4*tx+3 and +64
    const int ty = t >> 4;           // rows 8*ty..8*ty+7
    const int r0 = blockIdx.x * TR;

    float acc[8][8];
    #pragma unroll
    for (int i = 0; i < 8; ++i)
        #pragma unroll
        for (int j = 0; j < 8; ++j) acc[i][j] = 0.f;

    for (int kc = 0; kc < DF; kc += KC) {
        // ---- stage X chunk transposed: 128 rows x 32 k ----
        float4 xv4[4];
        #pragma unroll
        for (int l = 0; l < 4; ++l) {
            int flat = l * 256 + t;            // 0..1023
            int r    = flat & 127;
            int dl   = (flat >> 7) * 4;        // 0,4,...,28
            float4 v = make_float4(0.f, 0.f, 0.f, 0.f);
            if (r0 + r < N) v = *(const float4*)(X + (size_t)(r0 + r) * DF + kc + dl);
            xv4[l] = v;
        }
        float4 wv4[4];
        #pragma unroll
        for (int l = 0; l < 4; ++l) {
            int flat = l * 256 + t;
            int c    = flat & 127;
            int dl   = (flat >> 7) * 4;
            wv4[l] = *(const float4*)(W + (size_t)c * DF + kc + dl);
        }
        #pragma unroll
        for (int l = 0; l < 4; ++l) {
            int flat = l * 256 + t;
            int r    = flat & 127;
            int dl   = (flat >> 7) * 4;
            Xs[(dl + 0) * 128 + r] = xv4[l].x;
            Xs[(dl + 1) * 128 + r] = xv4[l].y;
            Xs[(dl + 2) * 128 + r] = xv4[l].z;
            Xs[(dl + 3) * 128 + r] = xv4[l].w;
            Ws[(dl + 0) * 128 + r] = wv4[l].x;
            Ws[(dl + 1) * 128 + r] = wv4[l].y;
            Ws[(dl + 2) * 128 + r] = wv4[l].z;
            Ws[(dl + 3) * 128 + r] = wv4[l].w;
        }
        __syncthreads();

        // ---- accumulate: per k, 4 b128 LDS reads + 64 FMA ----
        #pragma unroll
        for (int k = 0; k < KC; ++k) {
            float4 x0 = *(const float4*)(Xs + k * 128 + 8 * ty);
            float4 x1 = *(const float4*)(Xs + k * 128 + 8 * ty + 4);
            float4 w0 = *(const float4*)(Ws + k * 128 + 4 * tx);
            float4 w1 = *(const float4*)(Ws + k * 128 + 4 * tx + 64);
            float xr[8] = {x0.x, x0.y, x0.z, x0.w, x1.x, x1.y, x1.z, x1.w};
            float wc[8] = {w0.x, w0.y, w0.z, w0.w, w1.x, w1.y, w1.z, w1.w};
            #pragma unroll
            for (int i = 0; i < 8; ++i)
                #pragma unroll
                for (int j = 0; j < 8; ++j)
                    acc[i][j] += xr[i] * wc[j];
        }
        __syncthreads();
    }

    // ---- epilogue: bias + two float4 stores per row (full-line coalesced) ----
    float4 b0 = *(const float4*)(bias + 4 * tx);
    float4 b1 = *(const float4*)(bias + 4 * tx + 64);
    #pragma unroll
    for (int i = 0; i < 8; ++i) {
        int gr = r0 + 8 * ty + i;
        if (gr < N) {
            float4 o0, o1;
            o0.x = acc[i][0] + b0.x; o0.y = acc[i][1] + b0.y;
            o0.z = acc[i][2] + b0.z; o0.w = acc[i][3] + b0.w;
            o1.x = acc[i][4] + b1.x; o1.y = acc[i][5] + b1.y;
            o1.z = acc[i][6] + b1.z; o1.w = acc[i][7] + b1.w;
            *(float4*)(S + (size_t)gr * DF + 4 * tx)      = o0;
            *(float4*)(S + (size_t)gr * DF + 4 * tx + 64) = o1;
        }
    }
}

// ---------------------------------------------------------------------------
// Kernel 2: CSR row pointers + packed edge metadata {byte_offset, val_bits}.
// ---------------------------------------------------------------------------
__global__ __launch_bounds__(256)
void build_meta_kernel(const int* __restrict__ arow, const int* __restrict__ acol,
                       const float* __restrict__ aval,
                       int* __restrict__ rowptr, int2* __restrict__ pk,
                       int N, int E)
{
    int e = blockIdx.x * 256 + threadIdx.x;
    if (e >= E) return;
    pk[e] = make_int2(acol[e] << 9, __float_as_int(aval[e]));  // col*DF*4 bytes
    int r = arow[e];
    int rprev = (e == 0) ? -1 : arow[e - 1];
    for (int n = rprev + 1; n <= r; ++n) rowptr[n] = e;
    if (e == E - 1) {
        for (int n = r + 1; n <= N; ++n) rowptr[n] = E;
    }
}

// ---------------------------------------------------------------------------
// Kernel 3: out[n][:] = tanh( sum_e val[e]*S[col[e]][:] ) per CSR segment.
// One 64-lane wave per node; node id forced into SGPR via readfirstlane so
// rowptr/pk reads become s_load (scalar pipe, zero VALU). Gather is
// global_load_dwordx2 with constant lane offset off an SGPR base -> zero
// per-edge vector address math. 4 edges in flight, 2 acc chains.
// ---------------------------------------------------------------------------
__global__ __launch_bounds__(256)
void agg_tanh_kernel(const float* __restrict__ S, const int* __restrict__ rowptr,
                     const int2* __restrict__ pk, float* __restrict__ out, int Nn)
{
    const int n = __builtin_amdgcn_readfirstlane(blockIdx.x * 4 + (threadIdx.x >> 6));
    if (n >= Nn) return;
    const int lane = threadIdx.x & 63;
    const int l8   = lane * 8;

    const int start = rowptr[n];
    const int end   = rowptr[n + 1];
    const char* Sb  = (const char*)S;

    float2 a0; a0.x = 0.f; a0.y = 0.f;
    float2 a1; a1.x = 0.f; a1.y = 0.f;

    int e = start;
    for (; e + 4 <= end; e += 4) {
        int2 p0 = pk[e + 0];
        int2 p1 = pk[e + 1];
        int2 p2 = pk[e + 2];
        int2 p3 = pk[e + 3];
        float2 s0 = *(const float2*)(Sb + (size_t)(unsigned)p0.x + l8);
        float2 s1 = *(const float2*)(Sb + (size_t)(unsigned)p1.x + l8);
        float2 s2 = *(const float2*)(Sb + (size_t)(unsigned)p2.x + l8);
        float2 s3 = *(const float2*)(Sb + (size_t)(unsigned)p3.x + l8);
        float v0 = __int_as_float(p0.y), v1 = __int_as_float(p1.y);
        float v2 = __int_as_float(p2.y), v3 = __int_as_float(p3.y);
        a0.x += v0 * s0.x; a0.y += v0 * s0.y;
        a1.x += v1 * s1.x; a1.y += v1 * s1.y;
        a0.x += v2 * s2.x; a0.y += v2 * s2.y;
        a1.x += v3 * s3.x; a1.y += v3 * s3.y;
    }
    for (; e < end; ++e) {
        int2 p = pk[e];
        float2 s = *(const float2*)(Sb + (size_t)(unsigned)p.x + l8);
        float v = __int_as_float(p.y);
        a0.x += v * s.x; a0.y += v * s.y;
    }

    float2 o;
    o.x = tanhf(a0.x + a1.x);
    o.y = tanhf(a0.y + a1.y);
    *(float2*)(out + (size_t)n * DF + lane * 2) = o;
}

// ---------------------------------------------------------------------------
extern "C" void kernel_launch(void* const* d_in, const int* in_sizes, int n_in,
                              void* d_out, int out_size, void* d_ws, size_t ws_size,
                              hipStream_t stream)
{
    const float* X    = (const float*)d_in[0];   // [N, 128]
    const float* W    = (const float*)d_in[1];   // [128, 128]
    const float* bias = (const float*)d_in[2];   // [128]
    const int*   arow = (const int*)  d_in[3];   // [E] sorted
    const int*   acol = (const int*)  d_in[4];   // [E]
    const float* aval = (const float*)d_in[5];   // [E]
    float* out = (float*)d_out;

    const int N = in_sizes[0] / DF;
    const int E = in_sizes[3];

    // ws layout: S [N*128 f32] | rowptr [N+2 ints, keeps pk 8B-aligned] | pk [E int2]
    float* S      = (float*)d_ws;
    int*   rowptr = (int*)d_ws + (size_t)N * DF;
    int2*  pk     = (int2*)(rowptr + (N + 2));

    build_meta_kernel<<<(E + 255) / 256, 256, 0, stream>>>(arow, acol, aval,
                                                           rowptr, pk, N, E);

    gemm_bias_kernel<<<(N + TR - 1) / TR, 256, 0, stream>>>(X, W, bias, S, N);

    agg_tanh_kernel<<<(N + 3) / 4, 256, 0, stream>>>(S, rowptr, pk, out, N);
}